// Round 1
// baseline (193.621 us; speedup 1.0000x reference)
//
#include <hip/hip_runtime.h>
#include <hip/hip_bf16.h>
#include <stdint.h>

// Problem: scores[b,q,k] = dot(Q[b,q,:],K[b,k,:]) / (max(|Q_row|,eps)*max(|K_row|,eps)),
//          masked to -1e9 where mask[b,k]==0.
// B=4, Sq=Sk=2048, D=1024, fp32 in/out. Threshold is ~2e7 (2% of mask magnitude)
// => bf16 MFMA precision is more than sufficient.

constexpr int B_  = 4;
constexpr int SQ  = 2048;
constexpr int SK  = 2048;
constexpr int D_  = 1024;
constexpr int BM  = 128;
constexpr int BN  = 128;
constexpr int BK  = 32;
constexpr int LDK = 48;   // LDS row stride in bf16 elems: 96 B (16B-aligned, ~conflict-free)

typedef __attribute__((ext_vector_type(8))) short   short8;  // 8 bf16 = 4 VGPRs (MFMA A/B frag)
typedef __attribute__((ext_vector_type(4))) float   f32x4;
typedef __attribute__((ext_vector_type(4))) unsigned uint4v;

// Truncating fp32->bf16 pack of a pair into one dword (low short = first elem).
// v_perm_b32: one instruction per 2 elements. Truncation error irrelevant vs threshold.
__device__ inline unsigned pack_bf16(float lo, float hi) {
  union { float f; unsigned u; } a, b;
  a.f = lo; b.f = hi;
  return __builtin_amdgcn_perm(b.u, a.u, 0x07060302u);
}

__global__ __launch_bounds__(256, 2) void ca_gemm(
    const float* __restrict__ Q,    // [B][SQ][D]
    const float* __restrict__ Km,   // [B][SK][D]
    const int*   __restrict__ mask, // [B][SK]
    float*       __restrict__ out)  // [B][SQ][SK]
{
  __shared__ __align__(16) short As[BM * LDK];
  __shared__ __align__(16) short Bs[BN * LDK];
  __shared__ float ssA_part[256];
  __shared__ float ssB_part[256];
  __shared__ float invA[BM];
  __shared__ float invB[BN];

  const int tid  = threadIdx.x;
  const int lane = tid & 63;
  const int w    = tid >> 6;
  const int b    = blockIdx.z;
  const int tm0  = blockIdx.y * BM;   // block row base (Sq)
  const int tn0  = blockIdx.x * BN;   // block col base (Sk)

  // Staging: thread t loads 16 consecutive fp32 of row (t>>1), k-offset (t&1)*16,
  // for BOTH the A (Q) tile and B (K) tile each K-iter.
  const int ra = tid >> 1;
  const int ka = (tid & 1) * 16;

  const float* qp = Q  + ((size_t)b * SQ + tm0 + ra) * D_ + ka;
  const float* kp = Km + ((size_t)b * SK + tn0 + ra) * D_ + ka;

  f32x4 zero4 = {0.0f, 0.0f, 0.0f, 0.0f};
  f32x4 acc[4][4];
  #pragma unroll
  for (int i = 0; i < 4; ++i)
    #pragma unroll
    for (int j = 0; j < 4; ++j) acc[i][j] = zero4;

  // fp32 sum-of-squares accumulated during staging (full K traversed per block,
  // so row/col norms come for free — no extra HBM traffic, no workspace).
  float ssA = 0.0f, ssB = 0.0f;

  // wave -> 64x64 quadrant; MFMA 16x16x32 lane mapping:
  //   A frag: A[m = lane&15][k = (lane>>4)*8 + j]
  //   C/D   : col = lane&15, row = (lane>>4)*4 + reg
  const int wm = (w >> 1) * 64;
  const int wn = (w & 1) * 64;
  const int lr = lane & 15;
  const int lq = lane >> 4;

  short* aw = &As[ra * LDK + ka];
  short* bw = &Bs[ra * LDK + ka];

  for (int k0 = 0; k0 < D_; k0 += BK) {
    f32x4 av[4], bv[4];
    #pragma unroll
    for (int i = 0; i < 4; ++i) av[i] = *(const f32x4*)(qp + 4 * i);
    #pragma unroll
    for (int i = 0; i < 4; ++i) bv[i] = *(const f32x4*)(kp + 4 * i);
    qp += BK; kp += BK;

    unsigned pa[8], pb[8];
    #pragma unroll
    for (int i = 0; i < 4; ++i) {
      pa[2*i]   = pack_bf16(av[i].x, av[i].y);
      pa[2*i+1] = pack_bf16(av[i].z, av[i].w);
      pb[2*i]   = pack_bf16(bv[i].x, bv[i].y);
      pb[2*i+1] = pack_bf16(bv[i].z, bv[i].w);
      ssA += av[i].x*av[i].x + av[i].y*av[i].y + av[i].z*av[i].z + av[i].w*av[i].w;
      ssB += bv[i].x*bv[i].x + bv[i].y*bv[i].y + bv[i].z*bv[i].z + bv[i].w*bv[i].w;
    }

    __syncthreads();  // previous iter's fragment reads done before overwrite
    {
      uint4v wa0 = {pa[0], pa[1], pa[2], pa[3]};
      uint4v wa1 = {pa[4], pa[5], pa[6], pa[7]};
      uint4v wb0 = {pb[0], pb[1], pb[2], pb[3]};
      uint4v wb1 = {pb[4], pb[5], pb[6], pb[7]};
      *(uint4v*)(aw)     = wa0;
      *(uint4v*)(aw + 8) = wa1;
      *(uint4v*)(bw)     = wb0;
      *(uint4v*)(bw + 8) = wb1;
    }
    __syncthreads();  // writes visible

    short8 af[4], bf[4];
    #pragma unroll
    for (int t = 0; t < 4; ++t)
      af[t] = *(const short8*)&As[(wm + t * 16 + lr) * LDK + lq * 8];
    #pragma unroll
    for (int t = 0; t < 4; ++t)
      bf[t] = *(const short8*)&Bs[(wn + t * 16 + lr) * LDK + lq * 8];

    #pragma unroll
    for (int i = 0; i < 4; ++i)
      #pragma unroll
      for (int j = 0; j < 4; ++j)
        acc[i][j] = __builtin_amdgcn_mfma_f32_16x16x32_bf16(af[i], bf[j], acc[i][j], 0, 0, 0);
  }

  // ---- norm finalize: ss parts -> 1/max(sqrt(ss),eps) per local row/col ----
  ssA_part[tid] = ssA;
  ssB_part[tid] = ssB;
  __syncthreads();
  if (tid < BM) {
    float s = ssA_part[2 * tid] + ssA_part[2 * tid + 1];
    invA[tid] = 1.0f / fmaxf(sqrtf(s), 1e-8f);
  } else {
    int r = tid - BM;
    float s = ssB_part[2 * r] + ssB_part[2 * r + 1];
    invB[r] = 1.0f / fmaxf(sqrtf(s), 1e-8f);
  }
  __syncthreads();

  // ---- epilogue: scale + mask + store ----
  #pragma unroll
  for (int tn = 0; tn < 4; ++tn) {
    const int lc = wn + tn * 16 + lr;
    const int gc = tn0 + lc;
    const int mk = mask[b * SK + gc];
    const float ib = invB[lc];
    #pragma unroll
    for (int tm = 0; tm < 4; ++tm) {
      const int lrow = wm + tm * 16 + lq * 4;
      #pragma unroll
      for (int r = 0; r < 4; ++r) {
        float v = mk ? acc[tm][tn][r] * invA[lrow + r] * ib : -1000000000.0f;
        out[((size_t)b * SQ + tm0 + lrow + r) * SK + gc] = v;
      }
    }
  }
}

extern "C" void kernel_launch(void* const* d_in, const int* in_sizes, int n_in,
                              void* d_out, int out_size, void* d_ws, size_t ws_size,
                              hipStream_t stream) {
  const float* Q    = (const float*)d_in[0];
  const float* Km   = (const float*)d_in[1];
  const int*   mask = (const int*)d_in[2];
  float*       out  = (float*)d_out;

  dim3 grid(SK / BN, SQ / BM, B_);   // 16 x 16 x 4 = 1024 blocks
  ca_gemm<<<grid, dim3(256), 0, stream>>>(Q, Km, mask, out);
}

// Round 2
// 167.174 us; speedup vs baseline: 1.1582x; 1.1582x over previous
//
#include <hip/hip_runtime.h>
#include <hip/hip_bf16.h>
#include <stdint.h>

// scores[b,q,k] = dot(Q[b,q,:],K[b,k,:]) / (max(|Qrow|,eps)*max(|Krow|,eps)); mask==0 -> -1e9
// B=4, Sq=Sk=2048, D=1024, fp32 in/out. bf16 MFMA precision verified OK (R1 absmax 1.5e-3).
//
// R2: two-pass m97 structure.
//  Pass 1: fp32 -> bf16 into d_ws + fp32 row norms (free: one extra read of data we touch anyway).
//  Pass 2: bf16 GEMM, global_load_lds width=16 staging (no VGPR round-trip, half the tile bytes).
// Fallback (ws too small): R1 single-kernel with LDK=40 (fixes 4-way bank conflict of LDK=48).

constexpr int B_  = 4;
constexpr int SQ  = 2048;
constexpr int SK  = 2048;
constexpr int D_  = 1024;
constexpr int BM  = 128;
constexpr int BN  = 128;
constexpr int BK  = 32;

typedef __attribute__((ext_vector_type(8))) short    short8;
typedef __attribute__((ext_vector_type(4))) float    f32x4;
typedef __attribute__((ext_vector_type(4))) unsigned uint4v;
typedef unsigned int u32;

__device__ inline unsigned pack_bf16(float lo, float hi) {
  union { float f; unsigned u; } a, b;
  a.f = lo; b.f = hi;
  return __builtin_amdgcn_perm(b.u, a.u, 0x07060302u);
}

__device__ inline void async_ld16(const void* g, void* l) {
  __builtin_amdgcn_global_load_lds((const __attribute__((address_space(1))) u32*)g,
                                   (__attribute__((address_space(3))) u32*)l, 16, 0, 0);
}

// ---------------- Pass 1: convert + norms ----------------
// One wave per row (1024 fp32). lane reads 64 B, writes 32 B bf16; wave-reduce sum-of-squares.
constexpr int ROWS_Q = B_ * SQ;           // 8192
constexpr int ROWS_T = B_ * (SQ + SK);    // 16384

__global__ __launch_bounds__(256) void convert_norm(
    const float* __restrict__ Q, const float* __restrict__ Km,
    unsigned short* __restrict__ Qb, unsigned short* __restrict__ Kb,
    float* __restrict__ invQ, float* __restrict__ invK)
{
  const int row  = blockIdx.x * 4 + (threadIdx.x >> 6);
  const int lane = threadIdx.x & 63;

  const float* src; unsigned short* dst; float* inv;
  if (row < ROWS_Q) {
    src = Q  + (size_t)row * D_;
    dst = Qb + (size_t)row * D_;
    inv = invQ + row;
  } else {
    int r = row - ROWS_Q;
    src = Km + (size_t)r * D_;
    dst = Kb + (size_t)r * D_;
    inv = invK + r;
  }

  const f32x4* s4 = (const f32x4*)(src + lane * 16);
  f32x4 v[4];
  #pragma unroll
  for (int i = 0; i < 4; ++i) v[i] = s4[i];

  float ss = 0.0f;
  unsigned p[8];
  #pragma unroll
  for (int i = 0; i < 4; ++i) {
    p[2*i]   = pack_bf16(v[i].x, v[i].y);
    p[2*i+1] = pack_bf16(v[i].z, v[i].w);
    ss += v[i].x*v[i].x + v[i].y*v[i].y + v[i].z*v[i].z + v[i].w*v[i].w;
  }
  uint4v w0 = {p[0], p[1], p[2], p[3]};
  uint4v w1 = {p[4], p[5], p[6], p[7]};
  uint4v* d4 = (uint4v*)(dst + lane * 16);
  d4[0] = w0; d4[1] = w1;

  #pragma unroll
  for (int off = 32; off > 0; off >>= 1) ss += __shfl_xor(ss, off);
  if (lane == 0) *inv = 1.0f / fmaxf(sqrtf(ss), 1e-8f);
}

// ---------------- Pass 2: bf16 GEMM (m97 structure) ----------------
__global__ __launch_bounds__(256, 2) void ca_gemm_bf(
    const unsigned short* __restrict__ Qb,   // [B][SQ][D] bf16
    const unsigned short* __restrict__ Kb,   // [B][SK][D] bf16
    const float* __restrict__ invQ,          // [B][SQ]
    const float* __restrict__ invK,          // [B][SK]
    const int*   __restrict__ mask,          // [B][SK]
    float*       __restrict__ out)           // [B][SQ][SK]
{
  // Unpadded: global_load_lds writes wave-uniform base + lane*16B; rows must be contiguous.
  __shared__ __align__(16) unsigned short As[BM * BK];   // 8 KB
  __shared__ __align__(16) unsigned short Bs[BN * BK];   // 8 KB

  const int tid  = threadIdx.x;
  const int lane = tid & 63;
  const int w    = tid >> 6;
  const int b    = blockIdx.z;
  const int tm0  = blockIdx.y * BM;
  const int tn0  = blockIdx.x * BN;

  // Staging: lane i of wave w -> row (w*32 + inst*16 + (i>>2)), bytes [(i&3)*16, +16).
  const int srow = lane >> 2;
  const int soff = (lane & 3) * 16;    // byte offset within the 64 B (BK bf16) row

  const char* qrow = (const char*)(Qb + ((size_t)b * SQ + tm0 + w * 32 + srow) * D_) + soff;
  const char* krow = (const char*)(Kb + ((size_t)b * SK + tn0 + w * 32 + srow) * D_) + soff;
  const size_t rstep16 = (size_t)16 * D_ * 2;   // 16 rows in bytes

  unsigned short* ldsA0 = &As[(w * 32 +  0) * BK];
  unsigned short* ldsA1 = &As[(w * 32 + 16) * BK];
  unsigned short* ldsB0 = &Bs[(w * 32 +  0) * BK];
  unsigned short* ldsB1 = &Bs[(w * 32 + 16) * BK];

  f32x4 zero4 = {0.0f, 0.0f, 0.0f, 0.0f};
  f32x4 acc[4][4];
  #pragma unroll
  for (int i = 0; i < 4; ++i)
    #pragma unroll
    for (int j = 0; j < 4; ++j) acc[i][j] = zero4;

  const int wm = (w >> 1) * 64;
  const int wn = (w & 1) * 64;
  const int lr = lane & 15;
  const int lq = lane >> 4;

  for (int k0 = 0; k0 < D_; k0 += BK) {
    __syncthreads();   // previous iter's fragment reads complete before overwrite
    const size_t kb = (size_t)k0 * 2;
    async_ld16(qrow + kb,           ldsA0);
    async_ld16(qrow + kb + rstep16, ldsA1);
    async_ld16(krow + kb,           ldsB0);
    async_ld16(krow + kb + rstep16, ldsB1);
    __syncthreads();   // vmcnt drained by compiler before barrier -> tiles visible

    short8 af[4], bf[4];
    #pragma unroll
    for (int t = 0; t < 4; ++t)
      af[t] = *(const short8*)&As[(wm + t * 16 + lr) * BK + lq * 8];
    #pragma unroll
    for (int t = 0; t < 4; ++t)
      bf[t] = *(const short8*)&Bs[(wn + t * 16 + lr) * BK + lq * 8];

    #pragma unroll
    for (int i = 0; i < 4; ++i)
      #pragma unroll
      for (int j = 0; j < 4; ++j)
        acc[i][j] = __builtin_amdgcn_mfma_f32_16x16x32_bf16(af[i], bf[j], acc[i][j], 0, 0, 0);
  }

  // Epilogue: scale by 1/(|q||k|), mask, store. C/D: col=lane&15, row=(lane>>4)*4+reg.
  #pragma unroll
  for (int tn = 0; tn < 4; ++tn) {
    const int gc = tn0 + wn + tn * 16 + lr;
    const int mk = mask[b * SK + gc];
    const float ib = invK[b * SK + gc];
    #pragma unroll
    for (int tm = 0; tm < 4; ++tm) {
      const int lrow = wm + tm * 16 + lq * 4;
      #pragma unroll
      for (int r = 0; r < 4; ++r) {
        const float ia = invQ[b * SQ + tm0 + lrow + r];
        float v = mk ? acc[tm][tn][r] * ia * ib : -1000000000.0f;
        out[((size_t)b * SQ + tm0 + lrow + r) * SK + gc] = v;
      }
    }
  }
}

// ---------------- Fallback: R1 single-kernel, LDK=40 (conflict-free) ----------------
constexpr int LDK = 40;  // 20 dwords; 16-lane b128 phases tile all 32 banks exactly 2x (free)

__global__ __launch_bounds__(256, 2) void ca_gemm(
    const float* __restrict__ Q, const float* __restrict__ Km,
    const int* __restrict__ mask, float* __restrict__ out)
{
  __shared__ __align__(16) short As[BM * LDK];
  __shared__ __align__(16) short Bs[BN * LDK];
  __shared__ float ssA_part[256];
  __shared__ float ssB_part[256];
  __shared__ float invA[BM];
  __shared__ float invB[BN];

  const int tid  = threadIdx.x;
  const int lane = tid & 63;
  const int w    = tid >> 6;
  const int b    = blockIdx.z;
  const int tm0  = blockIdx.y * BM;
  const int tn0  = blockIdx.x * BN;

  const int ra = tid >> 1;
  const int ka = (tid & 1) * 16;

  const float* qp = Q  + ((size_t)b * SQ + tm0 + ra) * D_ + ka;
  const float* kp = Km + ((size_t)b * SK + tn0 + ra) * D_ + ka;

  f32x4 zero4 = {0.0f, 0.0f, 0.0f, 0.0f};
  f32x4 acc[4][4];
  #pragma unroll
  for (int i = 0; i < 4; ++i)
    #pragma unroll
    for (int j = 0; j < 4; ++j) acc[i][j] = zero4;

  float ssA = 0.0f, ssB = 0.0f;

  const int wm = (w >> 1) * 64;
  const int wn = (w & 1) * 64;
  const int lr = lane & 15;
  const int lq = lane >> 4;

  short* aw = &As[ra * LDK + ka];
  short* bw = &Bs[ra * LDK + ka];

  for (int k0 = 0; k0 < D_; k0 += BK) {
    f32x4 av[4], bv[4];
    #pragma unroll
    for (int i = 0; i < 4; ++i) av[i] = *(const f32x4*)(qp + 4 * i);
    #pragma unroll
    for (int i = 0; i < 4; ++i) bv[i] = *(const f32x4*)(kp + 4 * i);
    qp += BK; kp += BK;

    unsigned pa[8], pb[8];
    #pragma unroll
    for (int i = 0; i < 4; ++i) {
      pa[2*i]   = pack_bf16(av[i].x, av[i].y);
      pa[2*i+1] = pack_bf16(av[i].z, av[i].w);
      pb[2*i]   = pack_bf16(bv[i].x, bv[i].y);
      pb[2*i+1] = pack_bf16(bv[i].z, bv[i].w);
      ssA += av[i].x*av[i].x + av[i].y*av[i].y + av[i].z*av[i].z + av[i].w*av[i].w;
      ssB += bv[i].x*bv[i].x + bv[i].y*bv[i].y + bv[i].z*bv[i].z + bv[i].w*bv[i].w;
    }

    __syncthreads();
    {
      uint4v wa0 = {pa[0], pa[1], pa[2], pa[3]};
      uint4v wa1 = {pa[4], pa[5], pa[6], pa[7]};
      uint4v wb0 = {pb[0], pb[1], pb[2], pb[3]};
      uint4v wb1 = {pb[4], pb[5], pb[6], pb[7]};
      *(uint4v*)(aw)     = wa0;
      *(uint4v*)(aw + 8) = wa1;
      *(uint4v*)(bw)     = wb0;
      *(uint4v*)(bw + 8) = wb1;
    }
    __syncthreads();

    short8 af[4], bf[4];
    #pragma unroll
    for (int t = 0; t < 4; ++t)
      af[t] = *(const short8*)&As[(wm + t * 16 + lr) * LDK + lq * 8];
    #pragma unroll
    for (int t = 0; t < 4; ++t)
      bf[t] = *(const short8*)&Bs[(wn + t * 16 + lr) * LDK + lq * 8];

    #pragma unroll
    for (int i = 0; i < 4; ++i)
      #pragma unroll
      for (int j = 0; j < 4; ++j)
        acc[i][j] = __builtin_amdgcn_mfma_f32_16x16x32_bf16(af[i], bf[j], acc[i][j], 0, 0, 0);
  }

  ssA_part[tid] = ssA;
  ssB_part[tid] = ssB;
  __syncthreads();
  if (tid < BM) {
    float s = ssA_part[2 * tid] + ssA_part[2 * tid + 1];
    invA[tid] = 1.0f / fmaxf(sqrtf(s), 1e-8f);
  } else {
    int r = tid - BM;
    float s = ssB_part[2 * r] + ssB_part[2 * r + 1];
    invB[r] = 1.0f / fmaxf(sqrtf(s), 1e-8f);
  }
  __syncthreads();

  #pragma unroll
  for (int tn = 0; tn < 4; ++tn) {
    const int lc = wn + tn * 16 + lr;
    const int gc = tn0 + lc;
    const int mk = mask[b * SK + gc];
    const float ib = invB[lc];
    #pragma unroll
    for (int tm = 0; tm < 4; ++tm) {
      const int lrow = wm + tm * 16 + lq * 4;
      #pragma unroll
      for (int r = 0; r < 4; ++r) {
        float v = mk ? acc[tm][tn][r] * invA[lrow + r] * ib : -1000000000.0f;
        out[((size_t)b * SQ + tm0 + lrow + r) * SK + gc] = v;
      }
    }
  }
}

extern "C" void kernel_launch(void* const* d_in, const int* in_sizes, int n_in,
                              void* d_out, int out_size, void* d_ws, size_t ws_size,
                              hipStream_t stream) {
  const float* Q    = (const float*)d_in[0];
  const float* Km   = (const float*)d_in[1];
  const int*   mask = (const int*)d_in[2];
  float*       out  = (float*)d_out;

  const size_t nQ   = (size_t)B_ * SQ * D_;        // elements
  const size_t nK   = (size_t)B_ * SK * D_;
  const size_t need = (nQ + nK) * 2                // bf16 copies
                    + (size_t)B_ * (SQ + SK) * 4;  // inv norms
  if (ws_size >= need) {
    unsigned short* Qb  = (unsigned short*)d_ws;
    unsigned short* Kb  = Qb + nQ;
    float*          iQ  = (float*)(Kb + nK);
    float*          iK  = iQ + (size_t)B_ * SQ;
    convert_norm<<<ROWS_T / 4, 256, 0, stream>>>(Q, Km, Qb, Kb, iQ, iK);
    dim3 grid(SK / BN, SQ / BM, B_);
    ca_gemm_bf<<<grid, dim3(256), 0, stream>>>(Qb, Kb, iQ, iK, mask, out);
  } else {
    dim3 grid(SK / BN, SQ / BM, B_);
    ca_gemm<<<grid, dim3(256), 0, stream>>>(Q, Km, mask, out);
  }
}